// Round 2
// baseline (163.209 us; speedup 1.0000x reference)
//
#include <hip/hip_runtime.h>

// Problem constants (from reference setup_inputs)
constexpr int Bb = 32;            // batch
constexpr int Cc = 64;            // channels
constexpr int HWi = 128 * 128;    // 16384 spatial per (b,c)
constexpr long long Nn = (long long)Bb * HWi;  // 524288 samples per channel
constexpr float EPS = 1e-5f;

constexpr int PARTIALS_FLOATS = Cc * Bb * 5;   // 10240
constexpr int PARAMS_OFF = PARTIALS_FLOATS;

using f4 = __attribute__((ext_vector_type(4))) float;

// ---------------- stage 1: per-(c,b) partial sums ----------------
__global__ __launch_bounds__(256) void cbn_stage1(
    const float* __restrict__ xr, const float* __restrict__ xi,
    float* __restrict__ partials) {
  const int blk = blockIdx.x;          // c*B + b
  const int c = blk / Bb;
  const int b = blk - c * Bb;
  const size_t base = ((size_t)b * Cc + c) * (size_t)HWi;
  const f4* __restrict__ r4 = (const f4*)(xr + base);
  const f4* __restrict__ i4 = (const f4*)(xi + base);

  float sr = 0.f, si = 0.f, srr = 0.f, sri = 0.f, sii = 0.f;
  const int tid = threadIdx.x;
  // HW/4 = 4096 float4s, 256 threads -> 16 iterations
  #pragma unroll 8
  for (int k = tid; k < HWi / 4; k += 256) {
    f4 a = r4[k];
    f4 m = i4[k];
    sr  += a.x + a.y + a.z + a.w;
    si  += m.x + m.y + m.z + m.w;
    srr += a.x * a.x + a.y * a.y + a.z * a.z + a.w * a.w;
    sii += m.x * m.x + m.y * m.y + m.z * m.z + m.w * m.w;
    sri += a.x * m.x + a.y * m.y + a.z * m.z + a.w * m.w;
  }

  // wave64 shuffle reduction
  #pragma unroll
  for (int off = 32; off >= 1; off >>= 1) {
    sr  += __shfl_down(sr, off);
    si  += __shfl_down(si, off);
    srr += __shfl_down(srr, off);
    sri += __shfl_down(sri, off);
    sii += __shfl_down(sii, off);
  }

  __shared__ float red[4][5];
  const int wave = tid >> 6, lane = tid & 63;
  if (lane == 0) {
    red[wave][0] = sr;  red[wave][1] = si;  red[wave][2] = srr;
    red[wave][3] = sri; red[wave][4] = sii;
  }
  __syncthreads();
  if (tid == 0) {
    float t0 = 0.f, t1 = 0.f, t2 = 0.f, t3 = 0.f, t4 = 0.f;
    #pragma unroll
    for (int w = 0; w < 4; ++w) {
      t0 += red[w][0]; t1 += red[w][1]; t2 += red[w][2];
      t3 += red[w][3]; t4 += red[w][4];
    }
    float* p = partials + (size_t)blk * 5;
    p[0] = t0; p[1] = t1; p[2] = t2; p[3] = t3; p[4] = t4;
  }
}

// ---------------- stage 2: per-channel params (1 block, 64 threads) ----------------
__global__ __launch_bounds__(64) void cbn_stage2(
    const float* __restrict__ partials,
    const float* __restrict__ gamma, const float* __restrict__ beta,
    float* __restrict__ params) {
  const int c = threadIdx.x;
  if (c >= Cc) return;
  double sr = 0, si = 0, srr = 0, sri = 0, sii = 0;
  for (int b = 0; b < Bb; ++b) {
    const float* p = partials + ((size_t)c * Bb + b) * 5;
    sr += p[0]; si += p[1]; srr += p[2]; sri += p[3]; sii += p[4];
  }
  const double N = (double)Nn;
  const double mr = sr / N, mi = si / N;
  const double a = (srr - N * mr * mr) / (N - 1.0) + (double)EPS;
  const double d = (sii - N * mi * mi) / (N - 1.0) + (double)EPS;
  const double bq = (sri - N * mr * mi) / (N - 1.0);
  // closed-form 2x2 SPD inverse sqrt: M^-1/2 = [[d+s,-b],[-b,a+s]]/(s*t)
  const double s = sqrt(a * d - bq * bq);
  const double t = sqrt(a + d + 2.0 * s);
  const double inv = 1.0 / (s * t);
  const double w00 = (d + s) * inv;
  const double w01 = -bq * inv;
  const double w11 = (a + s) * inv;
  const double g00 = gamma[c * 4 + 0], g01 = gamma[c * 4 + 1];
  const double g10 = gamma[c * 4 + 2], g11 = gamma[c * 4 + 3];
  const double G00 = g00 * w00 + g01 * w01;
  const double G01 = g00 * w01 + g01 * w11;
  const double G10 = g10 * w00 + g11 * w01;
  const double G11 = g10 * w01 + g11 * w11;
  const double br = (double)beta[c * 2 + 0] - G00 * mr - G01 * mi;
  const double bi = (double)beta[c * 2 + 1] - G10 * mr - G11 * mi;
  float* q = params + c * 8;
  q[0] = (float)G00; q[1] = (float)G01; q[2] = (float)G10; q[3] = (float)G11;
  q[4] = (float)br;  q[5] = (float)bi;
}

// ---------------- stage 3: elementwise affine, interleaved output ----------------
// Non-temporal loads (data dead after this) + non-temporal stores (keep L3
// holding the inputs instead of the output).
constexpr size_t TOTAL4 = (size_t)Bb * Cc * HWi / 4;  // 8388608 float4s per input

__global__ __launch_bounds__(256) void cbn_stage3(
    const float* __restrict__ xr, const float* __restrict__ xi,
    const float* __restrict__ params, float* __restrict__ out) {
  const size_t stride = (size_t)gridDim.x * 256;
  f4* __restrict__ o = (f4*)out;
  for (size_t idx = (size_t)blockIdx.x * 256 + threadIdx.x; idx < TOTAL4;
       idx += stride) {
    const size_t e = idx * 4;
    const int c = (int)((e / (size_t)HWi) % (size_t)Cc);
    f4 a = __builtin_nontemporal_load((const f4*)xr + idx);
    f4 m = __builtin_nontemporal_load((const f4*)xi + idx);
    const float* p = params + c * 8;
    const float G00 = p[0], G01 = p[1], G10 = p[2], G11 = p[3], br = p[4],
                bi = p[5];
    f4 o0, o1;
    o0.x = G00 * a.x + G01 * m.x + br;
    o0.y = G10 * a.x + G11 * m.x + bi;
    o0.z = G00 * a.y + G01 * m.y + br;
    o0.w = G10 * a.y + G11 * m.y + bi;
    o1.x = G00 * a.z + G01 * m.z + br;
    o1.y = G10 * a.z + G11 * m.z + bi;
    o1.z = G00 * a.w + G01 * m.w + br;
    o1.w = G10 * a.w + G11 * m.w + bi;
    __builtin_nontemporal_store(o0, o + idx * 2 + 0);
    __builtin_nontemporal_store(o1, o + idx * 2 + 1);
  }
}

extern "C" void kernel_launch(void* const* d_in, const int* in_sizes, int n_in,
                              void* d_out, int out_size, void* d_ws, size_t ws_size,
                              hipStream_t stream) {
  const float* xr = (const float*)d_in[0];
  const float* xi = (const float*)d_in[1];
  const float* gamma = (const float*)d_in[2];
  const float* beta = (const float*)d_in[3];
  float* out = (float*)d_out;
  float* ws = (float*)d_ws;
  float* partials = ws;
  float* params = ws + PARAMS_OFF;

  cbn_stage1<<<Cc * Bb, 256, 0, stream>>>(xr, xi, partials);
  cbn_stage2<<<1, 64, 0, stream>>>(partials, gamma, beta, params);
  cbn_stage3<<<4096, 256, 0, stream>>>(xr, xi, params, out);
}

// Round 4
// 154.503 us; speedup vs baseline: 1.0563x; 1.0563x over previous
//
#include <hip/hip_runtime.h>

// Problem constants (from reference setup_inputs)
constexpr int Bb = 32;            // batch
constexpr int Cc = 64;            // channels
constexpr int HWi = 128 * 128;    // 16384 spatial per (b,c)
constexpr long long Nn = (long long)Bb * HWi;  // 524288 samples per channel
constexpr float EPS = 1e-5f;

using f4 = __attribute__((ext_vector_type(4))) float;

// ---------------- stage 1: per-(b,c) slab partial sums ----------------
// block blk covers slab (b*Cc + c) = blk; writes 5 partials at ws[slab*5].
__global__ __launch_bounds__(256) void cbn_stage1(
    const float* __restrict__ xr, const float* __restrict__ xi,
    float* __restrict__ partials) {
  const int slab = blockIdx.x;         // b*Cc + c
  const size_t base4 = (size_t)slab * (HWi / 4);
  const f4* __restrict__ r4 = (const f4*)xr + base4;
  const f4* __restrict__ i4 = (const f4*)xi + base4;

  float sr = 0.f, si = 0.f, srr = 0.f, sri = 0.f, sii = 0.f;
  const int tid = threadIdx.x;
  #pragma unroll 8
  for (int k = tid; k < HWi / 4; k += 256) {
    f4 a = r4[k];
    f4 m = i4[k];
    sr  += a.x + a.y + a.z + a.w;
    si  += m.x + m.y + m.z + m.w;
    srr += a.x * a.x + a.y * a.y + a.z * a.z + a.w * a.w;
    sii += m.x * m.x + m.y * m.y + m.z * m.z + m.w * m.w;
    sri += a.x * m.x + a.y * m.y + a.z * m.z + a.w * m.w;
  }

  #pragma unroll
  for (int off = 32; off >= 1; off >>= 1) {
    sr  += __shfl_down(sr, off);
    si  += __shfl_down(si, off);
    srr += __shfl_down(srr, off);
    sri += __shfl_down(sri, off);
    sii += __shfl_down(sii, off);
  }

  __shared__ float red[4][5];
  const int wave = tid >> 6, lane = tid & 63;
  if (lane == 0) {
    red[wave][0] = sr;  red[wave][1] = si;  red[wave][2] = srr;
    red[wave][3] = sri; red[wave][4] = sii;
  }
  __syncthreads();
  if (tid < 5) {
    partials[(size_t)slab * 5 + tid] =
        red[0][tid] + red[1][tid] + red[2][tid] + red[3][tid];
  }
}

// ---------------- stage 3: fold params (per block) + affine apply ----------
// 8192 blocks; block covers 1024 consecutive float4s = quarter of one slab.
// slab = blk>>2 = b*Cc + c, so c = slab & 63.
__global__ __launch_bounds__(256) void cbn_stage3(
    const float* __restrict__ xr, const float* __restrict__ xi,
    const float* __restrict__ partials,
    const float* __restrict__ gamma, const float* __restrict__ beta,
    float* __restrict__ out) {
  const int blk = blockIdx.x;
  const int c = (blk >> 2) & (Cc - 1);

  // fold the 32 per-batch partials of channel c (uniform -> scalar loads)
  double sr = 0, si = 0, srr = 0, sri = 0, sii = 0;
  #pragma unroll
  for (int b = 0; b < Bb; ++b) {
    const float* p = partials + ((size_t)b * Cc + c) * 5;
    sr += p[0]; si += p[1]; srr += p[2]; sri += p[3]; sii += p[4];
  }
  const double N = (double)Nn;
  const double mr = sr / N, mi = si / N;
  const double va = (srr - N * mr * mr) / (N - 1.0) + (double)EPS;
  const double vd = (sii - N * mi * mi) / (N - 1.0) + (double)EPS;
  const double vb = (sri - N * mr * mi) / (N - 1.0);
  // closed-form 2x2 SPD inverse sqrt: M^-1/2 = [[d+s,-b],[-b,a+s]]/(s*t)
  const double s = sqrt(va * vd - vb * vb);
  const double t = sqrt(va + vd + 2.0 * s);
  const double inv = 1.0 / (s * t);
  const double w00 = (vd + s) * inv;
  const double w01 = -vb * inv;
  const double w11 = (va + s) * inv;
  const double g00 = gamma[c * 4 + 0], g01 = gamma[c * 4 + 1];
  const double g10 = gamma[c * 4 + 2], g11 = gamma[c * 4 + 3];
  const float G00 = (float)(g00 * w00 + g01 * w01);
  const float G01 = (float)(g00 * w01 + g01 * w11);
  const float G10 = (float)(g10 * w00 + g11 * w01);
  const float G11 = (float)(g10 * w01 + g11 * w11);
  const float br = (float)((double)beta[c * 2 + 0] -
                           (g00 * w00 + g01 * w01) * mr -
                           (g00 * w01 + g01 * w11) * mi);
  const float bi = (float)((double)beta[c * 2 + 1] -
                           (g10 * w00 + g11 * w01) * mr -
                           (g10 * w01 + g11 * w11) * mi);

  // apply: 4 float4s per thread, contiguous within the quarter-slab
  const size_t idx0 = (size_t)blk * 1024 + threadIdx.x;
  f4* __restrict__ o = (f4*)out;
  #pragma unroll
  for (int k = 0; k < 4; ++k) {
    const size_t idx = idx0 + (size_t)k * 256;
    f4 a = ((const f4*)xr)[idx];
    f4 m = ((const f4*)xi)[idx];
    f4 o0, o1;
    o0.x = G00 * a.x + G01 * m.x + br;
    o0.y = G10 * a.x + G11 * m.x + bi;
    o0.z = G00 * a.y + G01 * m.y + br;
    o0.w = G10 * a.y + G11 * m.y + bi;
    o1.x = G00 * a.z + G01 * m.z + br;
    o1.y = G10 * a.z + G11 * m.z + bi;
    o1.z = G00 * a.w + G01 * m.w + br;
    o1.w = G10 * a.w + G11 * m.w + bi;
    o[idx * 2 + 0] = o0;
    o[idx * 2 + 1] = o1;
  }
}

extern "C" void kernel_launch(void* const* d_in, const int* in_sizes, int n_in,
                              void* d_out, int out_size, void* d_ws, size_t ws_size,
                              hipStream_t stream) {
  const float* xr = (const float*)d_in[0];
  const float* xi = (const float*)d_in[1];
  const float* gamma = (const float*)d_in[2];
  const float* beta = (const float*)d_in[3];
  float* out = (float*)d_out;
  float* partials = (float*)d_ws;

  cbn_stage1<<<Bb * Cc, 256, 0, stream>>>(xr, xi, partials);
  cbn_stage3<<<(Bb * Cc * HWi / 4) / 1024, 256, 0, stream>>>(
      xr, xi, partials, gamma, beta, out);
}